// Round 1
// baseline (159.684 us; speedup 1.0000x reference)
//
#include <hip/hip_runtime.h>
#include <hip/hip_bf16.h>

// Word2MatEncoder: out[b] = prod_{t=0..63} lookup_weight[sent[b,t]] (28x28 chain)
// One workgroup per batch row. Product R lives in LDS; next matrix is
// double-buffered in LDS with a depth-2 register prefetch of the global gather.
// 2x2 register tiling: 196 active threads, each owns a 2x2 output tile.

namespace {
constexpr int MD   = 28;    // matrix dim
constexpr int EMB  = 784;   // 28*28
constexpr int SEQ  = 64;
constexpr int BATCH = 256;
}

__global__ __launch_bounds__(256, 1)
void w2m_chain_kernel(const int* __restrict__ sent,
                      const float* __restrict__ W,
                      float* __restrict__ out) {
  __shared__ __align__(16) float R[EMB];       // running product, row-major 28x28
  __shared__ __align__(16) float Mb[2][EMB];   // double-buffered next matrix

  const int b   = blockIdx.x;
  const int tid = threadIdx.x;        // 0..255, 196 active
  const bool act = tid < 196;
  const int i  = tid / 14;            // row tile 0..13
  const int j  = tid % 14;            // col tile 0..13
  const int r0 = 2 * i;
  const int c0 = 2 * j;
  const int* srow = sent + b * SEQ;

  // Init R = M_0; prefetch M_1, M_2 into registers (depth-2 to cover ~900cy HBM miss).
  float4 pre0, pre1;
  if (act) {
    ((float4*)R)[tid] = ((const float4*)(W + (size_t)srow[0] * EMB))[tid];
    pre0 = ((const float4*)(W + (size_t)srow[1] * EMB))[tid];
    pre1 = ((const float4*)(W + (size_t)srow[2] * EMB))[tid];
  }

  float a00 = 0.f, a01 = 0.f, a10 = 0.f, a11 = 0.f;

  for (int t = 1; t < SEQ; ++t) {
    float* __restrict__ M = Mb[t & 1];
    if (act) ((float4*)M)[tid] = pre0;       // publish M_t
    pre0 = pre1;
    if (t + 2 < SEQ) {                        // issue gather for M_{t+2}
      if (act) pre1 = ((const float4*)(W + (size_t)srow[t + 2] * EMB))[tid];
    }
    __syncthreads();                          // M_t visible; prior R writes done

    a00 = a01 = a10 = a11 = 0.f;
    if (act) {
      const float* __restrict__ Ra = R + r0 * MD;        // 16B aligned (112*even)
      const float* __restrict__ Rb = Ra + MD;
      const float* __restrict__ Mc = M + c0;             // 8B aligned (c0 even)
#pragma unroll
      for (int k = 0; k < MD; ++k) {
        const float ra = Ra[k];
        const float rb = Rb[k];
        const float m0 = Mc[k * MD];
        const float m1 = Mc[k * MD + 1];
        a00 = fmaf(ra, m0, a00);
        a01 = fmaf(ra, m1, a01);
        a10 = fmaf(rb, m0, a10);
        a11 = fmaf(rb, m1, a11);
      }
    }
    __syncthreads();                          // all reads of R done

    if (act && t < SEQ - 1) {                 // write back new R (skip on last step)
      R[r0 * MD + c0]          = a00;
      R[r0 * MD + c0 + 1]      = a01;
      R[(r0 + 1) * MD + c0]     = a10;
      R[(r0 + 1) * MD + c0 + 1] = a11;
    }
  }

  if (act) {
    float* __restrict__ o = out + (size_t)b * EMB;
    o[r0 * MD + c0]           = a00;
    o[r0 * MD + c0 + 1]       = a01;
    o[(r0 + 1) * MD + c0]     = a10;
    o[(r0 + 1) * MD + c0 + 1] = a11;
  }
}

extern "C" void kernel_launch(void* const* d_in, const int* in_sizes, int n_in,
                              void* d_out, int out_size, void* d_ws, size_t ws_size,
                              hipStream_t stream) {
  const int*   sent = (const int*)d_in[0];     // (256, 64) int32
  const float* W    = (const float*)d_in[1];   // (30001, 784) f32
  float*       out  = (float*)d_out;           // (256, 784) f32
  (void)in_sizes; (void)n_in; (void)out_size; (void)d_ws; (void)ws_size;

  w2m_chain_kernel<<<BATCH, 256, 0, stream>>>(sent, W, out);
}

// Round 2
// 141.475 us; speedup vs baseline: 1.1287x; 1.1287x over previous
//
#include <hip/hip_runtime.h>
#include <hip/hip_bf16.h>

// Word2MatEncoder: out[b] = prod_{t=0..63} lookup_weight[sent[b,t]] (28x28 chain)
//
// Kernel 1 (w2m_partial): 256 batches x 8 segments, one 64-thread (1-wave)
//   block per segment. Computes the product of 8 gathered matrices with a
//   4x4-register-tiled LDS matmul (49 active lanes). Running product kept
//   TRANSPOSED in LDS (Rt[k][r]) so both operands are read as conflict-free
//   ds_read_b128 (banks stride 4 across lanes; 7-way broadcast is free).
//   Single wave => no __syncthreads; wave-order LDS semantics + compiler
//   waitcnts give correctness. Gather is reg-staged with 1-step prefetch.
//   Even segments written transposed to ws so kernel 2 needs no transposes.
//
// Kernel 2 (w2m_combine): per batch, tree-combine the 8 partials:
//   level0: 4 waves x (P0*P1 .. P6*P7), level1: 2 waves, level2: 1 wave -> out.

typedef float f32x4 __attribute__((ext_vector_type(4)));

namespace {
constexpr int MD  = 28;
constexpr int EMB = 784;
constexpr int SEQ = 64;
constexpr int BATCH = 256;
constexpr int SEG = 8;   // segments per batch
constexpr int LEN = 8;   // matrices per segment
}

// acc[rr][cc] = sum_k A[k][r0+rr] * B[k][c0+cc]
// A is a transposed product  (At[k][r]), B is row-major (B[k][c]).
__device__ __forceinline__ void kloop(const float* __restrict__ A,
                                      const float* __restrict__ B,
                                      int r0, int c0,
                                      f32x4& a0, f32x4& a1, f32x4& a2, f32x4& a3) {
  f32x4 z = {0.f, 0.f, 0.f, 0.f};
  a0 = a1 = a2 = a3 = z;
#pragma unroll
  for (int k = 0; k < MD; ++k) {
    f32x4 rv = *reinterpret_cast<const f32x4*>(A + k * MD + r0);
    f32x4 mv = *reinterpret_cast<const f32x4*>(B + k * MD + c0);
    a0 += rv[0] * mv;
    a1 += rv[1] * mv;
    a2 += rv[2] * mv;
    a3 += rv[3] * mv;
  }
}

// store transposed: D[c][r] = acc[r][c]  (D becomes a valid next-step A operand)
__device__ __forceinline__ void store_T(float* __restrict__ D, int r0, int c0,
                                        const f32x4& a0, const f32x4& a1,
                                        const f32x4& a2, const f32x4& a3) {
#pragma unroll
  for (int cc = 0; cc < 4; ++cc) {
    f32x4 v = { a0[cc], a1[cc], a2[cc], a3[cc] };
    *reinterpret_cast<f32x4*>(D + (c0 + cc) * MD + r0) = v;
  }
}

// store row-major: D[r][c] = acc[r][c]
__device__ __forceinline__ void store_N(float* __restrict__ D, int r0, int c0,
                                        const f32x4& a0, const f32x4& a1,
                                        const f32x4& a2, const f32x4& a3) {
  *reinterpret_cast<f32x4*>(D + (r0 + 0) * MD + c0) = a0;
  *reinterpret_cast<f32x4*>(D + (r0 + 1) * MD + c0) = a1;
  *reinterpret_cast<f32x4*>(D + (r0 + 2) * MD + c0) = a2;
  *reinterpret_cast<f32x4*>(D + (r0 + 3) * MD + c0) = a3;
}

__global__ __launch_bounds__(64, 1)
void w2m_partial(const int* __restrict__ sent,
                 const float* __restrict__ W,
                 float* __restrict__ ws) {
  __shared__ __align__(16) float Ms[2][EMB];  // double-buffered gathered matrix
  __shared__ __align__(16) float Rt[2][EMB];  // running product, transposed

  const int blk   = blockIdx.x;
  const int batch = blk >> 3;
  const int seg   = blk & 7;
  const int lane  = threadIdx.x;          // 0..63, one wave
  const bool act  = lane < 49;
  const int i = lane / 7, j = lane % 7;   // valid only under act
  const int r0 = 4 * i, c0 = 4 * j;
  const int* srow = sent + batch * SEQ + seg * LEN;

  f32x4 sA0, sA1, sA2, sA3;               // stage slot A (even t)
  f32x4 sB0, sB1, sB2, sB3;               // stage slot B (odd t)

  auto gload = [&](int t, f32x4& v0, f32x4& v1, f32x4& v2, f32x4& v3) {
    const f32x4* src = reinterpret_cast<const f32x4*>(W + (size_t)srow[t] * EMB);
    v0 = src[lane];
    v1 = src[64 + lane];
    v2 = src[128 + lane];
    if (lane < 4) v3 = src[192 + lane];   // 784 = 3*256 + 16 floats
  };
  auto lwrite = [&](float* dst, const f32x4& v0, const f32x4& v1,
                    const f32x4& v2, const f32x4& v3) {
    f32x4* d = reinterpret_cast<f32x4*>(dst);
    d[lane] = v0;
    d[64 + lane] = v1;
    d[128 + lane] = v2;
    if (lane < 4) d[192 + lane] = v3;
  };

  // Prologue: M0 -> Ms[0]; Rt[0] = I; prefetch M1 -> slot B.
  gload(0, sA0, sA1, sA2, sA3);
  if (act) {
#pragma unroll
    for (int cc = 0; cc < 4; ++cc) {
      int d = (c0 + cc) - r0;
      f32x4 v = { d == 0 ? 1.f : 0.f, d == 1 ? 1.f : 0.f,
                  d == 2 ? 1.f : 0.f, d == 3 ? 1.f : 0.f };
      *reinterpret_cast<f32x4*>(&Rt[0][(c0 + cc) * MD + r0]) = v;
    }
  }
  lwrite(Ms[0], sA0, sA1, sA2, sA3);
  gload(1, sB0, sB1, sB2, sB3);

  f32x4 a0, a1, a2, a3;
#pragma unroll 1
  for (int tp = 0; tp < LEN; tp += 2) {
    // ---- even step t = tp: A = Rt[0], B = Ms[0] -> Rt[1]
    lwrite(Ms[1], sB0, sB1, sB2, sB3);          // publish M_{tp+1} (load 1 step old)
    if (tp + 2 < LEN) gload(tp + 2, sA0, sA1, sA2, sA3);
    if (act) {
      kloop(Rt[0], Ms[0], r0, c0, a0, a1, a2, a3);
      store_T(Rt[1], r0, c0, a0, a1, a2, a3);
    }
    // ---- odd step t = tp+1: A = Rt[1], B = Ms[1] -> Rt[0] (or ws at t=7)
    if (tp + 2 < LEN) lwrite(Ms[0], sA0, sA1, sA2, sA3);  // publish M_{tp+2}
    if (tp + 3 < LEN) gload(tp + 3, sB0, sB1, sB2, sB3);
    if (act) {
      kloop(Rt[1], Ms[1], r0, c0, a0, a1, a2, a3);
      if (tp + 1 < LEN - 1) {
        store_T(Rt[0], r0, c0, a0, a1, a2, a3);
      } else {
        float* pb = ws + (size_t)(batch * SEG + seg) * EMB;
        if (seg & 1) store_N(pb, r0, c0, a0, a1, a2, a3);  // odd: row-major (B-side)
        else         store_T(pb, r0, c0, a0, a1, a2, a3);  // even: transposed (A-side)
      }
    }
  }
}

__global__ __launch_bounds__(256, 1)
void w2m_combine(const float* __restrict__ ws, float* __restrict__ out) {
  __shared__ __align__(16) float P[SEG][EMB];  // staged partials (even seg transposed)
  __shared__ __align__(16) float Q[4][EMB];
  __shared__ __align__(16) float Rl[2][EMB];

  const int batch = blockIdx.x;
  const int tid   = threadIdx.x;
  const int w     = tid >> 6;
  const int lane  = tid & 63;
  const bool act  = lane < 49;
  const int i = lane / 7, j = lane % 7;
  const int r0 = 4 * i, c0 = 4 * j;

  {
    const f32x4* src = reinterpret_cast<const f32x4*>(ws + (size_t)batch * SEG * EMB);
    f32x4* dst = reinterpret_cast<f32x4*>(&P[0][0]);
    for (int u = tid; u < SEG * EMB / 4; u += 256) dst[u] = src[u];
  }
  __syncthreads();

  f32x4 a0, a1, a2, a3;
  // level 0: Q[w] = P[2w] * P[2w+1]
  if (act) {
    kloop(P[2 * w], P[2 * w + 1], r0, c0, a0, a1, a2, a3);
    if (w & 1) store_N(Q[w], r0, c0, a0, a1, a2, a3);
    else       store_T(Q[w], r0, c0, a0, a1, a2, a3);
  }
  __syncthreads();
  // level 1: Rl[w] = Q[2w] * Q[2w+1]
  if (w < 2 && act) {
    kloop(Q[2 * w], Q[2 * w + 1], r0, c0, a0, a1, a2, a3);
    if (w & 1) store_N(Rl[w], r0, c0, a0, a1, a2, a3);
    else       store_T(Rl[w], r0, c0, a0, a1, a2, a3);
  }
  __syncthreads();
  // level 2: out = Rl[0] * Rl[1]
  if (w == 0 && act) {
    kloop(Rl[0], Rl[1], r0, c0, a0, a1, a2, a3);
    store_N(out + (size_t)batch * EMB, r0, c0, a0, a1, a2, a3);
  }
}

extern "C" void kernel_launch(void* const* d_in, const int* in_sizes, int n_in,
                              void* d_out, int out_size, void* d_ws, size_t ws_size,
                              hipStream_t stream) {
  const int*   sent = (const int*)d_in[0];    // (256, 64) int32
  const float* W    = (const float*)d_in[1];  // (30001, 784) f32
  float*       out  = (float*)d_out;          // (256, 784) f32
  float*       ws   = (float*)d_ws;           // needs 2048*784*4 = 6.4 MB
  (void)in_sizes; (void)n_in; (void)out_size; (void)ws_size;

  w2m_partial<<<BATCH * SEG, 64, 0, stream>>>(sent, W, ws);
  w2m_combine<<<BATCH, 256, 0, stream>>>(ws, out);
}